// Round 1
// baseline (3334.267 us; speedup 1.0000x reference)
//
#include <hip/hip_runtime.h>

#define BDIM 4
#define SDIM 2048
#define DMODEL 1024
#define NHEAD 16
#define HDIM 64
#define MTOT (BDIM*SDIM)          // 8192

// C = A[M,1024] * W[N,1024]^T * scale
// mode 0: C row-major [M, 1024]
// mode 1: C in head layout [B][NHEAD][SDIM][HDIM]
__global__ __launch_bounds__(256) void gemm_nt_kernel(
    const float* __restrict__ A, const float* __restrict__ W,
    float* __restrict__ C, float scale, int mode)
{
    __shared__ float As[64][33];
    __shared__ float Ws[64][33];
    const int tid = threadIdx.x;
    const int m0 = blockIdx.y * 64;
    const int n0 = blockIdx.x * 64;
    const int tx = tid & 15, ty = tid >> 4;

    float acc[4][4] = {};

    for (int k0 = 0; k0 < DMODEL; k0 += 32) {
        // stage A tile (64x32) and W tile (64x32): 512 float4 each, 2/thread
        #pragma unroll
        for (int i = 0; i < 2; ++i) {
            const int idx = tid + i * 256;      // 0..511
            const int row = idx >> 3;
            const int c4  = (idx & 7) * 4;
            const float4 av = *reinterpret_cast<const float4*>(
                &A[(size_t)(m0 + row) * DMODEL + k0 + c4]);
            As[row][c4+0] = av.x; As[row][c4+1] = av.y;
            As[row][c4+2] = av.z; As[row][c4+3] = av.w;
            const float4 wv = *reinterpret_cast<const float4*>(
                &W[(size_t)(n0 + row) * DMODEL + k0 + c4]);
            Ws[row][c4+0] = wv.x; Ws[row][c4+1] = wv.y;
            Ws[row][c4+2] = wv.z; Ws[row][c4+3] = wv.w;
        }
        __syncthreads();
        #pragma unroll
        for (int kk = 0; kk < 32; ++kk) {
            float a[4], b[4];
            #pragma unroll
            for (int i = 0; i < 4; ++i) a[i] = As[ty*4+i][kk];
            #pragma unroll
            for (int j = 0; j < 4; ++j) b[j] = Ws[tx*4+j][kk];
            #pragma unroll
            for (int i = 0; i < 4; ++i)
                #pragma unroll
                for (int j = 0; j < 4; ++j)
                    acc[i][j] = fmaf(a[i], b[j], acc[i][j]);
        }
        __syncthreads();
    }

    if (mode == 0) {
        #pragma unroll
        for (int i = 0; i < 4; ++i) {
            const int m = m0 + ty*4 + i;
            float4 o;
            o.x = acc[i][0]*scale; o.y = acc[i][1]*scale;
            o.z = acc[i][2]*scale; o.w = acc[i][3]*scale;
            *reinterpret_cast<float4*>(&C[(size_t)m * DMODEL + n0 + tx*4]) = o;
        }
    } else {
        const int h  = n0 >> 6;             // whole 64-wide tile is inside one head
        const int dh = (n0 & 63) + tx*4;
        #pragma unroll
        for (int i = 0; i < 4; ++i) {
            const int m = m0 + ty*4 + i;
            const int b = m >> 11;          // /SDIM
            const int s = m & (SDIM - 1);
            float4 o;
            o.x = acc[i][0]*scale; o.y = acc[i][1]*scale;
            o.z = acc[i][2]*scale; o.w = acc[i][3]*scale;
            *reinterpret_cast<float4*>(
                &C[(((size_t)(b*NHEAD + h) * SDIM + s) << 6) + dh]) = o;
        }
    }
}

// Flash-style causal attention.
// Q,K,V: [B][NHEAD][SDIM][HDIM] fp32 (Q pre-scaled by 1/sqrt(DMODEL)).
// Out:   [B][SDIM][DMODEL] fp32.
// Block: 32 q-rows; iterate 64-row KV tiles. 256 threads: r=tid/8 (row),
// g=tid%8 (8-col group of output / 8-col group of scores).
__global__ __launch_bounds__(256) void attn_kernel(
    const float* __restrict__ Q, const float* __restrict__ K,
    const float* __restrict__ V, float* __restrict__ Oout)
{
    __shared__ float Qs[32][65];
    __shared__ float Ks[64][65];
    __shared__ float Vs[64][64];
    __shared__ float Ps[32][65];

    const int tid = threadIdx.x;
    const int qt = blockIdx.x;
    const int bh = blockIdx.y;                 // b*NHEAD + h
    const int q0 = qt * 32;
    const int r = tid >> 3;                    // 0..31
    const int g = tid & 7;                     // 0..7

    const size_t base = (size_t)bh * SDIM * HDIM;

    // stage Q tile (32 x 64)
    for (int i = tid; i < 32 * 16; i += 256) {
        const int row = i >> 4, c4 = (i & 15) * 4;
        const float4 v = *reinterpret_cast<const float4*>(
            &Q[base + (size_t)(q0 + row) * HDIM + c4]);
        Qs[row][c4+0] = v.x; Qs[row][c4+1] = v.y;
        Qs[row][c4+2] = v.z; Qs[row][c4+3] = v.w;
    }

    float O[8] = {};
    float m_run = -3.0e38f, l_run = 0.0f;

    const int nkt = (q0 + 31) / 64 + 1;
    for (int kt = 0; kt < nkt; ++kt) {
        const int k0 = kt * 64;
        __syncthreads();   // previous-iter K/V/P fully consumed; Q writes visible
        for (int i = tid; i < 64 * 16; i += 256) {
            const int row = i >> 4, c4 = (i & 15) * 4;
            const float4 kv = *reinterpret_cast<const float4*>(
                &K[base + (size_t)(k0 + row) * HDIM + c4]);
            Ks[row][c4+0] = kv.x; Ks[row][c4+1] = kv.y;
            Ks[row][c4+2] = kv.z; Ks[row][c4+3] = kv.w;
            const float4 vv = *reinterpret_cast<const float4*>(
                &V[base + (size_t)(k0 + row) * HDIM + c4]);
            *reinterpret_cast<float4*>(&Vs[row][c4]) = vv;
        }
        __syncthreads();

        // scores for my 8 columns
        float s[8];
        #pragma unroll
        for (int j = 0; j < 8; ++j) {
            const int c = g*8 + j;
            float a = 0.f;
            #pragma unroll
            for (int d = 0; d < 64; ++d)
                a = fmaf(Qs[r][d], Ks[c][d], a);
            s[j] = (k0 + c > q0 + r) ? -1.0e30f : a;
        }
        // online softmax
        float mx = s[0];
        #pragma unroll
        for (int j = 1; j < 8; ++j) mx = fmaxf(mx, s[j]);
        #pragma unroll
        for (int off = 1; off < 8; off <<= 1)
            mx = fmaxf(mx, __shfl_xor(mx, off));
        const float m_new = fmaxf(m_run, mx);
        float psum = 0.f;
        #pragma unroll
        for (int j = 0; j < 8; ++j) { s[j] = __expf(s[j] - m_new); psum += s[j]; }
        #pragma unroll
        for (int off = 1; off < 8; off <<= 1)
            psum += __shfl_xor(psum, off);
        const float alpha = __expf(m_run - m_new);
        l_run = l_run * alpha + psum;
        m_run = m_new;
        #pragma unroll
        for (int j = 0; j < 8; ++j) O[j] *= alpha;
        #pragma unroll
        for (int j = 0; j < 8; ++j) Ps[r][g*8+j] = s[j];
        __syncthreads();

        // O += P * V
        #pragma unroll 8
        for (int k = 0; k < 64; ++k) {
            const float p = Ps[r][k];
            #pragma unroll
            for (int j = 0; j < 8; ++j)
                O[j] = fmaf(p, Vs[k][g*8+j], O[j]);
        }
    }

    // write attention output into [B][S][DMODEL]
    const int b = bh >> 4, h = bh & 15;
    const float inv = 1.0f / l_run;
    float4 o0, o1;
    o0.x = O[0]*inv; o0.y = O[1]*inv; o0.z = O[2]*inv; o0.w = O[3]*inv;
    o1.x = O[4]*inv; o1.y = O[5]*inv; o1.z = O[6]*inv; o1.w = O[7]*inv;
    const size_t ob = (size_t)(b*SDIM + q0 + r) * DMODEL + h*HDIM + g*8;
    *reinterpret_cast<float4*>(&Oout[ob])     = o0;
    *reinterpret_cast<float4*>(&Oout[ob + 4]) = o1;
}

extern "C" void kernel_launch(void* const* d_in, const int* in_sizes, int n_in,
                              void* d_out, int out_size, void* d_ws, size_t ws_size,
                              hipStream_t stream) {
    const float* x     = (const float*)d_in[0];
    // d_in[1] = causal mask (deterministic triu, applied analytically — unused)
    const float* w_q   = (const float*)d_in[2];
    const float* w_k   = (const float*)d_in[3];
    const float* w_v   = (const float*)d_in[4];
    const float* w_out = (const float*)d_in[5];
    float* out = (float*)d_out;

    const size_t NELEM = (size_t)BDIM * SDIM * DMODEL;   // 8,388,608
    float* Qw  = (float*)d_ws;
    float* Kw  = Qw + NELEM;
    float* Vw  = Kw + NELEM;
    float* ATT = Vw + NELEM;
    // requires ws_size >= 4 * NELEM * 4 = 134,217,728 bytes

    const dim3 gg(DMODEL / 64, MTOT / 64);   // (16, 128)
    gemm_nt_kernel<<<gg, 256, 0, stream>>>(x, w_q, Qw, 0.03125f, 1);  // 1/sqrt(1024)
    gemm_nt_kernel<<<gg, 256, 0, stream>>>(x, w_k, Kw, 1.0f, 1);
    gemm_nt_kernel<<<gg, 256, 0, stream>>>(x, w_v, Vw, 1.0f, 1);
    attn_kernel<<<dim3(SDIM / 32, BDIM * NHEAD), 256, 0, stream>>>(Qw, Kw, Vw, ATT);
    gemm_nt_kernel<<<gg, 256, 0, stream>>>(ATT, w_out, out, 1.0f, 0);
}

// Round 3
// 795.435 us; speedup vs baseline: 4.1918x; 4.1918x over previous
//
#include <hip/hip_runtime.h>

#define BDIM 4
#define SDIM 2048
#define DMODEL 1024
#define NHEAD 16
#define HDIM 64
#define MTOT (BDIM*SDIM)          // 8192

typedef unsigned short u16;
typedef __attribute__((ext_vector_type(8))) short bf16x8;
typedef __attribute__((ext_vector_type(4))) float f32x4;

__device__ __forceinline__ u16 f2bf(float f) {
  unsigned u = __builtin_bit_cast(unsigned, f);
  u += 0x7fffu + ((u >> 16) & 1u);   // RNE to bf16
  return (u16)(u >> 16);
}

// ---------------------------------------------------------------- cast fp32 -> bf16
__global__ __launch_bounds__(256) void cast_bf16_kernel(
    const float* __restrict__ src, u16* __restrict__ dst, int n4)
{
  const int i = blockIdx.x * 256 + threadIdx.x;
  if (i < n4) {
    const float4 v = reinterpret_cast<const float4*>(src)[i];
    unsigned long long w =
        (unsigned long long)f2bf(v.x)
      | ((unsigned long long)f2bf(v.y) << 16)
      | ((unsigned long long)f2bf(v.z) << 32)
      | ((unsigned long long)f2bf(v.w) << 48);
    reinterpret_cast<unsigned long long*>(dst)[i] = w;
  }
}

// ---------------------------------------------------------------- bf16 MFMA GEMM
// C = A[M,1024](bf16) * W[N=1024,K=1024](bf16)^T * scale
// mode 0: C fp32 row-major [M][1024]
// mode 1: C bf16 head layout [B][H][S][64]
// mode 2: C bf16 transposed head layout [B][H][64][S]   (for V)
__global__ __launch_bounds__(256) void gemm_bf16_kernel(
    const u16* __restrict__ A, const u16* __restrict__ W,
    void* __restrict__ C, float scale, int mode)
{
  __shared__ u16 As[128 * 32];
  __shared__ u16 Bs[128 * 32];

  const int tid = threadIdx.x;
  const int m0 = blockIdx.y * 128, n0 = blockIdx.x * 128;
  const int l  = tid & 63, wid = tid >> 6;
  const int wr = wid >> 1, wc = wid & 1;        // 2x2 waves -> 64x64 each
  const int lc = l & 15, lr = l >> 4;

  const f32x4 z4 = {0.f, 0.f, 0.f, 0.f};
  f32x4 acc[4][4];
  #pragma unroll
  for (int i = 0; i < 4; ++i)
    #pragma unroll
    for (int j = 0; j < 4; ++j) acc[i][j] = z4;

  for (int k0 = 0; k0 < DMODEL; k0 += 32) {
    // stage A/B tiles: 128x32 bf16 each, 16B per thread per step
    #pragma unroll
    for (int t = 0; t < 2; ++t) {
      const int s   = t * 256 + tid;      // 0..511
      const int row = s >> 2;
      const int u   = (s & 3) * 8;        // elem offset in row
      *reinterpret_cast<uint4*>(&As[row * 32 + u]) =
          *reinterpret_cast<const uint4*>(&A[(size_t)(m0 + row) * DMODEL + k0 + u]);
      *reinterpret_cast<uint4*>(&Bs[row * 32 + u]) =
          *reinterpret_cast<const uint4*>(&W[(size_t)(n0 + row) * DMODEL + k0 + u]);
    }
    __syncthreads();

    bf16x8 a[4], b[4];
    #pragma unroll
    for (int i = 0; i < 4; ++i)
      a[i] = *reinterpret_cast<const bf16x8*>(&As[(wr*64 + i*16 + lc) * 32 + lr*8]);
    #pragma unroll
    for (int j = 0; j < 4; ++j)
      b[j] = *reinterpret_cast<const bf16x8*>(&Bs[(wc*64 + j*16 + lc) * 32 + lr*8]);

    #pragma unroll
    for (int i = 0; i < 4; ++i)
      #pragma unroll
      for (int j = 0; j < 4; ++j)
        acc[i][j] = __builtin_amdgcn_mfma_f32_16x16x32_bf16(a[i], b[j], acc[i][j], 0, 0, 0);
    __syncthreads();
  }

  // epilogue — C/D layout: col = lc, row = lr*4 + j (verified m89/m91)
  #pragma unroll
  for (int mi = 0; mi < 4; ++mi)
    #pragma unroll
    for (int ni = 0; ni < 4; ++ni) {
      const int col = n0 + wc*64 + ni*16 + lc;
      #pragma unroll
      for (int j = 0; j < 4; ++j) {
        const int row = m0 + wr*64 + mi*16 + lr*4 + j;
        const float v = acc[mi][ni][j] * scale;
        if (mode == 0) {
          reinterpret_cast<float*>(C)[(size_t)row * DMODEL + col] = v;
        } else if (mode == 1) {
          const int b = row >> 11, s = row & (SDIM-1), h = col >> 6, dh = col & 63;
          reinterpret_cast<u16*>(C)[(((size_t)(b*NHEAD + h) * SDIM + s) << 6) + dh] = f2bf(v);
        } else {
          const int b = row >> 11, s = row & (SDIM-1), h = col >> 6, dh = col & 63;
          reinterpret_cast<u16*>(C)[(((size_t)(b*NHEAD + h) * HDIM + dh) << 11) + s] = f2bf(v);
        }
      }
    }
}

// ---------------------------------------------------------------- MFMA flash attention
// Qh,Kh: [B*H][S][64] bf16 (Q pre-scaled by log2e/32). Vt: [B*H][64][S] bf16.
// Ob: [B*S][1024] bf16. 4 waves/block, 16 q-rows per wave, KV tile = 64. Causal.
__global__ __launch_bounds__(256) void attn_mfma_kernel(
    const u16* __restrict__ Qh, const u16* __restrict__ Kh,
    const u16* __restrict__ Vt, u16* __restrict__ Ob)
{
  __shared__ u16 Plds[4 * 16 * 64];   // per-wave 16x64 bf16, XOR-swizzled

  const int tid = threadIdx.x, l = tid & 63, wid = tid >> 6;
  const int lc = l & 15, lr = l >> 4;
  const int qt = blockIdx.x, bh = blockIdx.y;
  const size_t base = (size_t)bh * SDIM * HDIM;   // same count for Kh and Vt
  const int qrow0 = qt * 64 + wid * 16;           // wave's first q row

  // Q fragments (held in regs for whole kernel). A-frag: m=lc, k=lr*8+j (contig-8)
  bf16x8 aq[2];
  #pragma unroll
  for (int kc = 0; kc < 2; ++kc)
    aq[kc] = *reinterpret_cast<const bf16x8*>(
        &Qh[base + (size_t)(qrow0 + lc) * HDIM + kc*32 + lr*8]);

  const f32x4 z4 = {0.f, 0.f, 0.f, 0.f};
  f32x4 o[4];
  #pragma unroll
  for (int dt = 0; dt < 4; ++dt) o[dt] = z4;
  float m_run[4], l_run[4];
  #pragma unroll
  for (int rr = 0; rr < 4; ++rr) { m_run[rr] = -1e30f; l_run[rr] = 0.f; }

  char* const myP = reinterpret_cast<char*>(&Plds[wid * 1024]);   // 2048 B region

  for (int t = 0; t <= qt; ++t) {
    const int kv0 = t * 64;

    // ---- S = Q K^T  (B-frag of K^T: n=lc -> kv col, k=lr*8+j -> d)
    f32x4 s[4];
    #pragma unroll
    for (int nt = 0; nt < 4; ++nt) s[nt] = z4;
    #pragma unroll
    for (int nt = 0; nt < 4; ++nt)
      #pragma unroll
      for (int kc = 0; kc < 2; ++kc) {
        const bf16x8 bk = *reinterpret_cast<const bf16x8*>(
            &Kh[base + (size_t)(kv0 + nt*16 + lc) * HDIM + kc*32 + lr*8]);
        s[nt] = __builtin_amdgcn_mfma_f32_16x16x32_bf16(aq[kc], bk, s[nt], 0, 0, 0);
      }

    // ---- causal mask (only the diagonal tile needs it)
    if (t == qt) {
      #pragma unroll
      for (int nt = 0; nt < 4; ++nt) {
        const int kvc = kv0 + nt*16 + lc;
        #pragma unroll
        for (int rr = 0; rr < 4; ++rr)
          if (kvc > qrow0 + lr*4 + rr) s[nt][rr] = -1e9f;
      }
    }

    // ---- online softmax (scores are in log2 domain; use exp2)
    float alpha[4];
    #pragma unroll
    for (int rr = 0; rr < 4; ++rr) {
      float mx = fmaxf(fmaxf(s[0][rr], s[1][rr]), fmaxf(s[2][rr], s[3][rr]));
      mx = fmaxf(mx, __shfl_xor(mx, 1));
      mx = fmaxf(mx, __shfl_xor(mx, 2));
      mx = fmaxf(mx, __shfl_xor(mx, 4));
      mx = fmaxf(mx, __shfl_xor(mx, 8));
      const float mn = fmaxf(m_run[rr], mx);
      alpha[rr] = exp2f(m_run[rr] - mn);
      float ps = 0.f;
      #pragma unroll
      for (int nt = 0; nt < 4; ++nt) {
        const float p = exp2f(s[nt][rr] - mn);
        s[nt][rr] = p;
        ps += p;
      }
      ps += __shfl_xor(ps, 1);
      ps += __shfl_xor(ps, 2);
      ps += __shfl_xor(ps, 4);
      ps += __shfl_xor(ps, 8);
      l_run[rr] = l_run[rr] * alpha[rr] + ps;
      m_run[rr] = mn;
    }

    // ---- rescale O (component j of o[dt] is q-row lr*4+j)
    #pragma unroll
    for (int dt = 0; dt < 4; ++dt)
      #pragma unroll
      for (int rr = 0; rr < 4; ++rr)
        o[dt][rr] *= alpha[rr];

    // ---- P: C-layout -> LDS (bf16, swizzled), read back as A-frags
    #pragma unroll
    for (int nt = 0; nt < 4; ++nt)
      #pragma unroll
      for (int rr = 0; rr < 4; ++rr) {
        const int row = lr*4 + rr, col = nt*16 + lc;
        const int byte = (row*128 + col*2) ^ ((row & 7) << 4);
        *reinterpret_cast<u16*>(myP + byte) = f2bf(s[nt][rr]);
      }
    bf16x8 pa[2];
    #pragma unroll
    for (int kc = 0; kc < 2; ++kc) {
      const int byte = (lc*128 + (kc*32 + lr*8)*2) ^ ((lc & 7) << 4);
      pa[kc] = *reinterpret_cast<const bf16x8*>(myP + byte);
    }

    // ---- O += P V  (B-frag of V from transposed-V global: n=lc -> d, k -> kv)
    #pragma unroll
    for (int dt = 0; dt < 4; ++dt)
      #pragma unroll
      for (int kc = 0; kc < 2; ++kc) {
        const bf16x8 bv = *reinterpret_cast<const bf16x8*>(
            &Vt[base + (size_t)(dt*16 + lc) * SDIM + kv0 + kc*32 + lr*8]);
        o[dt] = __builtin_amdgcn_mfma_f32_16x16x32_bf16(pa[kc], bv, o[dt], 0, 0, 0);
      }
  }

  // ---- epilogue: normalize, write bf16 [B][S][1024]
  const int b = bh >> 4, h = bh & 15;
  #pragma unroll
  for (int rr = 0; rr < 4; ++rr) {
    const float inv = 1.0f / l_run[rr];
    const int srow = qt*64 + wid*16 + lr*4 + rr;
    const size_t ob = ((size_t)(b * SDIM + srow)) * DMODEL + h * HDIM;
    #pragma unroll
    for (int dt = 0; dt < 4; ++dt)
      Ob[ob + dt*16 + lc] = f2bf(o[dt][rr] * inv);
  }
}

// ---------------------------------------------------------------- launch
extern "C" void kernel_launch(void* const* d_in, const int* in_sizes, int n_in,
                              void* d_out, int out_size, void* d_ws, size_t ws_size,
                              hipStream_t stream) {
  const float* x     = (const float*)d_in[0];
  // d_in[1] = causal mask (deterministic triu, applied analytically — unused)
  const float* w_q   = (const float*)d_in[2];
  const float* w_k   = (const float*)d_in[3];
  const float* w_v   = (const float*)d_in[4];
  const float* w_out = (const float*)d_in[5];
  float* out = (float*)d_out;

  const size_t NX = (size_t)MTOT * DMODEL;   // 8,388,608
  const size_t NW = (size_t)DMODEL * DMODEL; // 1,048,576
  u16* xb   = (u16*)d_ws;
  u16* wqb  = xb  + NX;
  u16* wkb  = wqb + NW;
  u16* wvb  = wkb + NW;
  u16* wob  = wvb + NW;
  u16* Qhd  = wob + NW;
  u16* Khd  = Qhd + NX;
  u16* Vtd  = Khd + NX;
  u16* attb = Vtd + NX;
  // total: 5*NX + 4*NW ushorts = 92.3 MB (fits ws)

  // casts
  cast_bf16_kernel<<<(int)(NX/4 + 255)/256, 256, 0, stream>>>(x, xb, (int)(NX/4));
  cast_bf16_kernel<<<(int)(NW/4 + 255)/256, 256, 0, stream>>>(w_q,   wqb, (int)(NW/4));
  cast_bf16_kernel<<<(int)(NW/4 + 255)/256, 256, 0, stream>>>(w_k,   wkb, (int)(NW/4));
  cast_bf16_kernel<<<(int)(NW/4 + 255)/256, 256, 0, stream>>>(w_v,   wvb, (int)(NW/4));
  cast_bf16_kernel<<<(int)(NW/4 + 255)/256, 256, 0, stream>>>(w_out, wob, (int)(NW/4));

  const dim3 gg(DMODEL / 128, MTOT / 128);   // (8, 64)
  // Q scaled by 1/sqrt(1024) * log2(e) so softmax runs in exp2 domain
  gemm_bf16_kernel<<<gg, 256, 0, stream>>>(xb, wqb, Qhd, 1.4426950408889634f / 32.0f, 1);
  gemm_bf16_kernel<<<gg, 256, 0, stream>>>(xb, wkb, Khd, 1.0f, 1);
  gemm_bf16_kernel<<<gg, 256, 0, stream>>>(xb, wvb, Vtd, 1.0f, 2);

  attn_mfma_kernel<<<dim3(SDIM / 64, BDIM * NHEAD), 256, 0, stream>>>(Qhd, Khd, Vtd, attb);

  gemm_bf16_kernel<<<gg, 256, 0, stream>>>(attb, wob, out, 1.0f, 0);
}

// Round 4
// 483.665 us; speedup vs baseline: 6.8937x; 1.6446x over previous
//
#include <hip/hip_runtime.h>

#define BDIM 4
#define SDIM 2048
#define DMODEL 1024
#define NHEAD 16
#define HDIM 64
#define MTOT (BDIM*SDIM)          // 8192

typedef unsigned short u16;
typedef __attribute__((ext_vector_type(8))) short bf16x8;
typedef __attribute__((ext_vector_type(4))) float f32x4;

__device__ __forceinline__ u16 f2bf(float f) {
  unsigned u = __builtin_bit_cast(unsigned, f);
  u += 0x7fffu + ((u >> 16) & 1u);   // RNE to bf16
  return (u16)(u >> 16);
}

// async global->LDS, 16B per lane. LDS dest is wave-uniform base + lane*16.
__device__ __forceinline__ void gload_lds16(const u16* g, u16* l) {
  __builtin_amdgcn_global_load_lds(
      (const __attribute__((address_space(1))) unsigned int*)g,
      (__attribute__((address_space(3))) unsigned int*)l, 16, 0, 0);
}

// ---------------------------------------------------------------- cast fp32 -> bf16
__global__ __launch_bounds__(256) void cast_bf16_kernel(
    const float* __restrict__ src, u16* __restrict__ dst, int n4)
{
  const int i = blockIdx.x * 256 + threadIdx.x;
  if (i < n4) {
    const float4 v = reinterpret_cast<const float4*>(src)[i];
    unsigned long long w =
        (unsigned long long)f2bf(v.x)
      | ((unsigned long long)f2bf(v.y) << 16)
      | ((unsigned long long)f2bf(v.z) << 32)
      | ((unsigned long long)f2bf(v.w) << 48);
    reinterpret_cast<unsigned long long*>(dst)[i] = w;
  }
}

// ---------------------------------------------------------------- bf16 MFMA GEMM
// C = A[M,1024](bf16) * W[N=1024,K=1024](bf16)^T * scale
// mode 0: C fp32 row-major [M][1024]
// mode 1: C bf16 head layout [B][H][S][64]
// mode 2: C bf16 transposed head layout [B][H][64][S]   (for V)
__global__ __launch_bounds__(256) void gemm_bf16_kernel(
    const u16* __restrict__ A, const u16* __restrict__ W,
    void* __restrict__ C, float scale, int mode)
{
  __shared__ u16 As[128 * 32];
  __shared__ u16 Bs[128 * 32];

  const int tid = threadIdx.x;
  const int m0 = blockIdx.y * 128, n0 = blockIdx.x * 128;
  const int l  = tid & 63, wid = tid >> 6;
  const int wr = wid >> 1, wc = wid & 1;        // 2x2 waves -> 64x64 each
  const int lc = l & 15, lr = l >> 4;
  // staging lane geometry: 1 inst = 64 lanes x 16B = 1KB = 16 rows of 64B
  const int ar = l >> 2;          // row within 16-row group
  const int ac = (l & 3) * 8;     // elem offset within 32-elem row

  const f32x4 z4 = {0.f, 0.f, 0.f, 0.f};
  f32x4 acc[4][4];
  #pragma unroll
  for (int i = 0; i < 4; ++i)
    #pragma unroll
    for (int j = 0; j < 4; ++j) acc[i][j] = z4;

  for (int k0 = 0; k0 < DMODEL; k0 += 32) {
    // stage A/B tiles (128x32 bf16 each) via global_load_lds, 2+2 insts/wave
    #pragma unroll
    for (int j = 0; j < 2; ++j) {
      const int row = wid * 32 + j * 16;
      gload_lds16(&A[(size_t)(m0 + row + ar) * DMODEL + k0 + ac], &As[row * 32]);
      gload_lds16(&W[(size_t)(n0 + row + ar) * DMODEL + k0 + ac], &Bs[row * 32]);
    }
    __syncthreads();   // drains vmcnt(0) -> staged data visible

    bf16x8 a[4], b[4];
    #pragma unroll
    for (int i = 0; i < 4; ++i)
      a[i] = *reinterpret_cast<const bf16x8*>(&As[(wr*64 + i*16 + lc) * 32 + lr*8]);
    #pragma unroll
    for (int j = 0; j < 4; ++j)
      b[j] = *reinterpret_cast<const bf16x8*>(&Bs[(wc*64 + j*16 + lc) * 32 + lr*8]);

    #pragma unroll
    for (int i = 0; i < 4; ++i)
      #pragma unroll
      for (int j = 0; j < 4; ++j)
        acc[i][j] = __builtin_amdgcn_mfma_f32_16x16x32_bf16(a[i], b[j], acc[i][j], 0, 0, 0);
    __syncthreads();
  }

  // epilogue — C/D layout: col = lc, row = lr*4 + j (verified m89/m91)
  #pragma unroll
  for (int mi = 0; mi < 4; ++mi)
    #pragma unroll
    for (int ni = 0; ni < 4; ++ni) {
      const int col = n0 + wc*64 + ni*16 + lc;
      #pragma unroll
      for (int j = 0; j < 4; ++j) {
        const int row = m0 + wr*64 + mi*16 + lr*4 + j;
        const float v = acc[mi][ni][j] * scale;
        if (mode == 0) {
          reinterpret_cast<float*>(C)[(size_t)row * DMODEL + col] = v;
        } else if (mode == 1) {
          const int b = row >> 11, s = row & (SDIM-1), h = col >> 6, dh = col & 63;
          reinterpret_cast<u16*>(C)[(((size_t)(b*NHEAD + h) * SDIM + s) << 6) + dh] = f2bf(v);
        } else {
          const int b = row >> 11, s = row & (SDIM-1), h = col >> 6, dh = col & 63;
          reinterpret_cast<u16*>(C)[(((size_t)(b*NHEAD + h) * HDIM + dh) << 11) + s] = f2bf(v);
        }
      }
    }
}

// ---------------------------------------------------------------- MFMA flash attention
// Qh,Kh: [B*H][S][64] bf16 (Q pre-scaled by log2e/32). Vt: [B*H][64][S] bf16.
// Ob: [B*S][1024] bf16. 4 waves/block, 16 q-rows per wave, KV tile = 64. Causal.
// K/V tiles staged in LDS (shared by all 4 waves), double-buffered, issue-early.
// LDS layout is XOR-swizzled (byte ^= (row&7)<<4) achieved by PRE-SWIZZLING the
// per-lane global source chunk (c' -> c'^(r&7)) while keeping LDS dest linear.
__global__ __launch_bounds__(256) void attn_mfma_kernel(
    const u16* __restrict__ Qh, const u16* __restrict__ Kh,
    const u16* __restrict__ Vt, u16* __restrict__ Ob)
{
  __shared__ u16 Ks[2][64 * 64];     // [kv][d], swizzled
  __shared__ u16 Vs[2][64 * 64];     // [d][kv], swizzled
  __shared__ u16 Plds[4 * 16 * 64];  // per-wave 16x64 bf16, XOR-swizzled

  const int tid = threadIdx.x, l = tid & 63, wid = tid >> 6;
  const int lc = l & 15, lr = l >> 4;
  const int qt = (int)gridDim.x - 1 - (int)blockIdx.x;   // heavy blocks first
  const int bh = blockIdx.y;
  const size_t base = (size_t)bh * SDIM * HDIM;   // same count for Kh and Vt
  const int qrow0 = qt * 64 + wid * 16;           // wave's first q row

  // staging lane geometry: 1 inst = 1KB = 8 rows of 128B; row-group base == 0 mod 8
  const int sr = l >> 3;                 // row within 8-row group (== r&7)
  const int sc = ((l & 7) ^ sr) * 8;     // pre-swizzled source elem offset

  // Q fragments (held in regs). A-frag: m=lc, k=lr*8+j (contig-8)
  bf16x8 aq[2];
  #pragma unroll
  for (int kc = 0; kc < 2; ++kc)
    aq[kc] = *reinterpret_cast<const bf16x8*>(
        &Qh[base + (size_t)(qrow0 + lc) * HDIM + kc*32 + lr*8]);

  const f32x4 z4 = {0.f, 0.f, 0.f, 0.f};
  f32x4 o[4];
  #pragma unroll
  for (int dt = 0; dt < 4; ++dt) o[dt] = z4;
  float m_run[4], l_run[4];
  #pragma unroll
  for (int rr = 0; rr < 4; ++rr) { m_run[rr] = -1e30f; l_run[rr] = 0.f; }

  char* const myP = reinterpret_cast<char*>(&Plds[wid * 1024]);   // 2048 B region

  const int nt = qt + 1;

  // ---- stage helper: wave stages its 16 K-rows and 16 V-d-rows (2+2 insts)
  #define STAGE(bufi, kv0s)                                                     \
    {                                                                           \
      _Pragma("unroll")                                                         \
      for (int j = 0; j < 2; ++j) {                                             \
        const int rg = wid * 16 + j * 8;                                        \
        gload_lds16(&Kh[base + (size_t)((kv0s) + rg + sr) * HDIM + sc],         \
                    &Ks[bufi][rg * 64]);                                        \
        gload_lds16(&Vt[base + (size_t)(rg + sr) * SDIM + (kv0s) + sc],         \
                    &Vs[bufi][rg * 64]);                                        \
      }                                                                         \
    }

  STAGE(0, 0);
  __syncthreads();   // vmcnt(0) drain + barrier: buf0 ready

  for (int t = 0; t < nt; ++t) {
    const int kv0 = t * 64;
    const int cur = t & 1;

    // issue next tile's loads early — they drain at the syncthreads at loop end
    if (t + 1 < nt) STAGE(cur ^ 1, kv0 + 64);

    // ---- S = Q K^T  (B-frag of K^T: n=lc -> kv col, k=lr*8+j -> d)
    f32x4 s[4];
    #pragma unroll
    for (int nt_ = 0; nt_ < 4; ++nt_) s[nt_] = z4;
    #pragma unroll
    for (int nt_ = 0; nt_ < 4; ++nt_) {
      const int r = nt_*16 + lc;
      #pragma unroll
      for (int kc = 0; kc < 2; ++kc) {
        const int cc = kc*4 + lr;
        const bf16x8 bk = *reinterpret_cast<const bf16x8*>(
            &Ks[cur][r*64 + ((cc ^ (r & 7)) * 8)]);
        s[nt_] = __builtin_amdgcn_mfma_f32_16x16x32_bf16(aq[kc], bk, s[nt_], 0, 0, 0);
      }
    }

    // ---- causal mask (only the diagonal tile needs it)
    if (t == qt) {
      #pragma unroll
      for (int nt_ = 0; nt_ < 4; ++nt_) {
        const int kvc = kv0 + nt_*16 + lc;
        #pragma unroll
        for (int rr = 0; rr < 4; ++rr)
          if (kvc > qrow0 + lr*4 + rr) s[nt_][rr] = -1e9f;
      }
    }

    // ---- online softmax (scores in log2 domain; exp2)
    float alpha[4];
    #pragma unroll
    for (int rr = 0; rr < 4; ++rr) {
      float mx = fmaxf(fmaxf(s[0][rr], s[1][rr]), fmaxf(s[2][rr], s[3][rr]));
      mx = fmaxf(mx, __shfl_xor(mx, 1));
      mx = fmaxf(mx, __shfl_xor(mx, 2));
      mx = fmaxf(mx, __shfl_xor(mx, 4));
      mx = fmaxf(mx, __shfl_xor(mx, 8));
      const float mn = fmaxf(m_run[rr], mx);
      alpha[rr] = exp2f(m_run[rr] - mn);
      float ps = 0.f;
      #pragma unroll
      for (int nt_ = 0; nt_ < 4; ++nt_) {
        const float p = exp2f(s[nt_][rr] - mn);
        s[nt_][rr] = p;
        ps += p;
      }
      ps += __shfl_xor(ps, 1);
      ps += __shfl_xor(ps, 2);
      ps += __shfl_xor(ps, 4);
      ps += __shfl_xor(ps, 8);
      l_run[rr] = l_run[rr] * alpha[rr] + ps;
      m_run[rr] = mn;
    }

    // ---- rescale O
    #pragma unroll
    for (int dt = 0; dt < 4; ++dt)
      #pragma unroll
      for (int rr = 0; rr < 4; ++rr)
        o[dt][rr] *= alpha[rr];

    // ---- P: C-layout -> LDS (bf16, swizzled), read back as A-frags
    #pragma unroll
    for (int nt_ = 0; nt_ < 4; ++nt_)
      #pragma unroll
      for (int rr = 0; rr < 4; ++rr) {
        const int row = lr*4 + rr, col = nt_*16 + lc;
        const int byte = (row*128 + col*2) ^ ((row & 7) << 4);
        *reinterpret_cast<u16*>(myP + byte) = f2bf(s[nt_][rr]);
      }
    bf16x8 pa[2];
    #pragma unroll
    for (int kc = 0; kc < 2; ++kc) {
      const int byte = (lc*128 + (kc*32 + lr*8)*2) ^ ((lc & 7) << 4);
      pa[kc] = *reinterpret_cast<const bf16x8*>(myP + byte);
    }

    // ---- O += P V  (B-frag of V from LDS: n=lc -> d, k=lr*8+j -> kv)
    #pragma unroll
    for (int dt = 0; dt < 4; ++dt) {
      const int rd = dt*16 + lc;
      #pragma unroll
      for (int kc = 0; kc < 2; ++kc) {
        const int cc = kc*4 + lr;
        const bf16x8 bv = *reinterpret_cast<const bf16x8*>(
            &Vs[cur][rd*64 + ((cc ^ (rd & 7)) * 8)]);
        o[dt] = __builtin_amdgcn_mfma_f32_16x16x32_bf16(pa[kc], bv, o[dt], 0, 0, 0);
      }
    }

    // all waves done with buf[cur]; next tile's DMA (into cur^1) drained here
    __syncthreads();
  }
  #undef STAGE

  // ---- epilogue: normalize, write bf16 [B][S][1024]
  const int b = bh >> 4, h = bh & 15;
  #pragma unroll
  for (int rr = 0; rr < 4; ++rr) {
    const float inv = 1.0f / l_run[rr];
    const int srow = qt*64 + wid*16 + lr*4 + rr;
    const size_t ob = ((size_t)(b * SDIM + srow)) * DMODEL + h * HDIM;
    #pragma unroll
    for (int dt = 0; dt < 4; ++dt)
      Ob[ob + dt*16 + lc] = f2bf(o[dt][rr] * inv);
  }
}

// ---------------------------------------------------------------- launch
extern "C" void kernel_launch(void* const* d_in, const int* in_sizes, int n_in,
                              void* d_out, int out_size, void* d_ws, size_t ws_size,
                              hipStream_t stream) {
  const float* x     = (const float*)d_in[0];
  // d_in[1] = causal mask (deterministic triu, applied analytically — unused)
  const float* w_q   = (const float*)d_in[2];
  const float* w_k   = (const float*)d_in[3];
  const float* w_v   = (const float*)d_in[4];
  const float* w_out = (const float*)d_in[5];
  float* out = (float*)d_out;

  const size_t NX = (size_t)MTOT * DMODEL;   // 8,388,608
  const size_t NW = (size_t)DMODEL * DMODEL; // 1,048,576
  u16* xb   = (u16*)d_ws;
  u16* wqb  = xb  + NX;
  u16* wkb  = wqb + NW;
  u16* wvb  = wkb + NW;
  u16* wob  = wvb + NW;
  u16* Qhd  = wob + NW;
  u16* Khd  = Qhd + NX;
  u16* Vtd  = Khd + NX;
  u16* attb = Vtd + NX;
  // total: 5*NX + 4*NW ushorts = 92.3 MB (fits ws)

  // casts
  cast_bf16_kernel<<<(int)(NX/4 + 255)/256, 256, 0, stream>>>(x, xb, (int)(NX/4));
  cast_bf16_kernel<<<(int)(NW/4 + 255)/256, 256, 0, stream>>>(w_q,   wqb, (int)(NW/4));
  cast_bf16_kernel<<<(int)(NW/4 + 255)/256, 256, 0, stream>>>(w_k,   wkb, (int)(NW/4));
  cast_bf16_kernel<<<(int)(NW/4 + 255)/256, 256, 0, stream>>>(w_v,   wvb, (int)(NW/4));
  cast_bf16_kernel<<<(int)(NW/4 + 255)/256, 256, 0, stream>>>(w_out, wob, (int)(NW/4));

  const dim3 gg(DMODEL / 128, MTOT / 128);   // (8, 64)
  // Q scaled by 1/sqrt(1024) * log2(e) so softmax runs in exp2 domain
  gemm_bf16_kernel<<<gg, 256, 0, stream>>>(xb, wqb, Qhd, 1.4426950408889634f / 32.0f, 1);
  gemm_bf16_kernel<<<gg, 256, 0, stream>>>(xb, wkb, Khd, 1.0f, 1);
  gemm_bf16_kernel<<<gg, 256, 0, stream>>>(xb, wvb, Vtd, 1.0f, 2);

  attn_mfma_kernel<<<dim3(SDIM / 64, BDIM * NHEAD), 256, 0, stream>>>(Qhd, Khd, Vtd, attb);

  gemm_bf16_kernel<<<gg, 256, 0, stream>>>(attb, wob, out, 1.0f, 0);
}

// Round 5
// 364.138 us; speedup vs baseline: 9.1566x; 1.3282x over previous
//
#include <hip/hip_runtime.h>

#define BDIM 4
#define SDIM 2048
#define DMODEL 1024
#define NHEAD 16
#define HDIM 64
#define MTOT (BDIM*SDIM)          // 8192

typedef unsigned short u16;
typedef unsigned int u32;
typedef __attribute__((ext_vector_type(8))) short bf16x8;
typedef __attribute__((ext_vector_type(4))) float f32x4;
typedef __attribute__((ext_vector_type(16))) float f32x16;
typedef __attribute__((ext_vector_type(4))) u32 u32x4;

__device__ __forceinline__ u16 f2bf(float f) {
  unsigned u = __builtin_bit_cast(unsigned, f);
  u += 0x7fffu + ((u >> 16) & 1u);   // RNE to bf16
  return (u16)(u >> 16);
}

// packed f32x2 -> bf16x2 (src0 -> low half). gfx950 VOP3.
__device__ __forceinline__ u32 cvtpk(float a, float b) {
  u32 r;
  asm("v_cvt_pk_bf16_f32 %0, %1, %2" : "=v"(r) : "v"(a), "v"(b));
  return r;
}

// async global->LDS, 16B per lane. LDS dest is wave-uniform base + lane*16.
__device__ __forceinline__ void gload_lds16(const u16* g, u16* l) {
  __builtin_amdgcn_global_load_lds(
      (const __attribute__((address_space(1))) unsigned int*)g,
      (__attribute__((address_space(3))) unsigned int*)l, 16, 0, 0);
}

// ---------------------------------------------------------------- cast fp32 -> bf16
__global__ __launch_bounds__(256) void cast_bf16_kernel(
    const float* __restrict__ src, u16* __restrict__ dst, int n4)
{
  const int i = blockIdx.x * 256 + threadIdx.x;
  if (i < n4) {
    const float4 v = reinterpret_cast<const float4*>(src)[i];
    unsigned long long w =
        (unsigned long long)f2bf(v.x)
      | ((unsigned long long)f2bf(v.y) << 16)
      | ((unsigned long long)f2bf(v.z) << 32)
      | ((unsigned long long)f2bf(v.w) << 48);
    reinterpret_cast<unsigned long long*>(dst)[i] = w;
  }
}

// ---------------------------------------------------------------- bf16 MFMA GEMM
// C = A[M,1024](bf16) * W[N=1024,K=1024](bf16)^T * scale
// mode 0: fp32 [M][1024]; mode 1: bf16 [B][H][S][64]; mode 2: bf16 [B][H][64][S]
// 2-phase double-buffered global_load_lds staging (T3 minimum).
__global__ __launch_bounds__(256) void gemm_bf16_kernel(
    const u16* __restrict__ A, const u16* __restrict__ W,
    void* __restrict__ C, float scale, int mode)
{
  __shared__ u16 As[2][128 * 32];
  __shared__ u16 Bs[2][128 * 32];

  const int tid = threadIdx.x;
  const int m0 = blockIdx.y * 128, n0 = blockIdx.x * 128;
  const int l  = tid & 63, wid = tid >> 6;
  const int wr = wid >> 1, wc = wid & 1;        // 2x2 waves -> 64x64 each
  const int lc = l & 15, lr = l >> 4;
  const int ar = l >> 2;          // staging: row within 16-row group
  const int ac = (l & 3) * 8;     // staging: elem offset in 32-elem row

  const f32x4 z4 = {0.f, 0.f, 0.f, 0.f};
  f32x4 acc[4][4];
  #pragma unroll
  for (int i = 0; i < 4; ++i)
    #pragma unroll
    for (int j = 0; j < 4; ++j) acc[i][j] = z4;

  #define GSTAGE(bufi, kk)                                                        \
    { _Pragma("unroll")                                                           \
      for (int j = 0; j < 2; ++j) {                                               \
        const int row = wid * 32 + j * 16;                                        \
        gload_lds16(&A[(size_t)(m0 + row + ar) * DMODEL + (kk) + ac],             \
                    &As[bufi][row * 32]);                                         \
        gload_lds16(&W[(size_t)(n0 + row + ar) * DMODEL + (kk) + ac],             \
                    &Bs[bufi][row * 32]);                                         \
      } }

  GSTAGE(0, 0);
  __syncthreads();

  for (int ks = 0; ks < DMODEL / 32; ++ks) {
    const int cur = ks & 1;
    if (ks + 1 < DMODEL / 32) GSTAGE(cur ^ 1, (ks + 1) * 32);

    bf16x8 a[4], b[4];
    #pragma unroll
    for (int i = 0; i < 4; ++i)
      a[i] = *reinterpret_cast<const bf16x8*>(&As[cur][(wr*64 + i*16 + lc) * 32 + lr*8]);
    #pragma unroll
    for (int j = 0; j < 4; ++j)
      b[j] = *reinterpret_cast<const bf16x8*>(&Bs[cur][(wc*64 + j*16 + lc) * 32 + lr*8]);

    #pragma unroll
    for (int i = 0; i < 4; ++i)
      #pragma unroll
      for (int j = 0; j < 4; ++j)
        acc[i][j] = __builtin_amdgcn_mfma_f32_16x16x32_bf16(a[i], b[j], acc[i][j], 0, 0, 0);
    __syncthreads();   // drains next tile's DMA; protects buf reuse
  }
  #undef GSTAGE

  // epilogue — C/D layout: col = lc, row = lr*4 + j
  #pragma unroll
  for (int mi = 0; mi < 4; ++mi)
    #pragma unroll
    for (int ni = 0; ni < 4; ++ni) {
      const int col = n0 + wc*64 + ni*16 + lc;
      #pragma unroll
      for (int j = 0; j < 4; ++j) {
        const int row = m0 + wr*64 + mi*16 + lr*4 + j;
        const float v = acc[mi][ni][j] * scale;
        if (mode == 0) {
          reinterpret_cast<float*>(C)[(size_t)row * DMODEL + col] = v;
        } else if (mode == 1) {
          const int b = row >> 11, s = row & (SDIM-1), h = col >> 6, dh = col & 63;
          reinterpret_cast<u16*>(C)[(((size_t)(b*NHEAD + h) * SDIM + s) << 6) + dh] = f2bf(v);
        } else {
          const int b = row >> 11, s = row & (SDIM-1), h = col >> 6, dh = col & 63;
          reinterpret_cast<u16*>(C)[(((size_t)(b*NHEAD + h) * HDIM + dh) << 11) + s] = f2bf(v);
        }
      }
    }
}

// ---------------------------------------------------------------- MFMA flash attention
// Swapped-operand 32x32 structure (T12): S^T = mfma(K, Q^T) so each lane owns one
// q-row (q = lane&31); softmax stats are lane-local scalars. O^T = mfma(V^T, P^T).
// Qh,Kh: [B*H][S][64] bf16 (Q pre-scaled by log2e/32). Vt: [B*H][64][S] bf16.
// Ob: [B*S][1024] bf16. 4 waves x 32 q-rows = 128 q/block; KV tile 64, dbuf LDS.
__global__ __launch_bounds__(256, 3) void attn_mfma_kernel(
    const u16* __restrict__ Qh, const u16* __restrict__ Kh,
    const u16* __restrict__ Vt, u16* __restrict__ Ob)
{
  __shared__ u16 Ks[2][64 * 64];   // [kv][d], byte ^= (kv&7)<<4
  __shared__ u16 Vs[2][64 * 64];   // [d][kv], byte ^= (d&7)<<4

  const int tid = threadIdx.x, l = tid & 63, wid = tid >> 6;
  const int q31 = l & 31, hi = l >> 5;
  const int qt = (int)gridDim.x - 1 - (int)blockIdx.x;   // heavy blocks first
  const int bh = blockIdx.y;
  const size_t base = (size_t)bh * SDIM * HDIM;
  const int qrow0 = qt * 128 + wid * 32;

  // staging lane geometry: 1 inst = 1KB = 8 rows x 128B; pre-swizzled source
  const int sr = l >> 3;
  const int sc = ((l & 7) ^ sr) * 8;

  // Q as B-frag: lane holds Q[qrow0+q31][kc*16 + hi*8 + j]
  bf16x8 aq[4];
  #pragma unroll
  for (int kc = 0; kc < 4; ++kc)
    aq[kc] = *reinterpret_cast<const bf16x8*>(
        &Qh[base + (size_t)(qrow0 + q31) * HDIM + kc*16 + hi*8]);

  f32x16 o[2], p[2];
  #pragma unroll
  for (int r = 0; r < 16; ++r) { o[0][r] = 0.f; o[1][r] = 0.f; }
  float m_run = -1e30f, l_run = 0.f;

  #define STAGE(bufi, kv0s)                                                     \
    { _Pragma("unroll")                                                         \
      for (int j = 0; j < 2; ++j) {                                             \
        const int rg = wid * 16 + j * 8;                                        \
        gload_lds16(&Kh[base + (size_t)((kv0s) + rg + sr) * HDIM + sc],         \
                    &Ks[bufi][rg * 64]);                                        \
        gload_lds16(&Vt[base + (size_t)(rg + sr) * SDIM + (kv0s) + sc],         \
                    &Vs[bufi][rg * 64]);                                        \
      } }

  const int nt = 2 * qt + 2;
  STAGE(0, 0);
  __syncthreads();

  for (int t = 0; t < nt; ++t) {
    const int kv0 = t * 64;
    const int cur = t & 1;
    if (t + 1 < nt) STAGE(cur ^ 1, kv0 + 64);   // issue-early; drains at barrier

    if (kv0 <= qrow0 + 31) {   // wave-uniform: skip fully-masked tiles
      // ---- S^T = K Q^T : D[kv, q=lane&31]
      #pragma unroll
      for (int kvb = 0; kvb < 2; ++kvb) {
        #pragma unroll
        for (int r = 0; r < 16; ++r) p[kvb][r] = 0.f;
        const int krow = kvb*32 + q31;
        #pragma unroll
        for (int kc = 0; kc < 4; ++kc) {
          const int byte = (krow*128 + kc*32 + hi*16) ^ ((krow & 7) << 4);
          const bf16x8 ak = *reinterpret_cast<const bf16x8*>(
              reinterpret_cast<const char*>(Ks[cur]) + byte);
          p[kvb] = __builtin_amdgcn_mfma_f32_32x32x16_bf16(ak, aq[kc], p[kvb], 0, 0, 0);
        }
      }

      // ---- causal mask (reg r holds kv = kv0 + kvb*32 + (r&3)+8*(r>>2)+4*hi)
      if (kv0 + 63 > qrow0) {
        const int q = qrow0 + q31;
        #pragma unroll
        for (int kvb = 0; kvb < 2; ++kvb)
          #pragma unroll
          for (int r = 0; r < 16; ++r) {
            const int kv = kv0 + kvb*32 + (r & 3) + 8*(r >> 2) + 4*hi;
            if (kv > q) p[kvb][r] = -1e9f;
          }
      }

      // ---- online softmax (log2 domain), lane-local + one lane^32 exchange
      float pm = -1e30f;
      #pragma unroll
      for (int r = 0; r < 16; ++r) {
        pm = fmaxf(pm, p[0][r]); pm = fmaxf(pm, p[1][r]);
      }
      pm = fmaxf(pm, __shfl_xor(pm, 32));
      float mn = m_run;
      if (!__all(pm - m_run <= 8.0f)) {      // defer-max (T13)
        mn = fmaxf(m_run, pm);
        const float al = __builtin_amdgcn_exp2f(m_run - mn);
        #pragma unroll
        for (int r = 0; r < 16; ++r) { o[0][r] *= al; o[1][r] *= al; }
        l_run *= al;
        m_run = mn;
      }
      float rs = 0.f;
      #pragma unroll
      for (int kvb = 0; kvb < 2; ++kvb)
        #pragma unroll
        for (int r = 0; r < 16; ++r) {
          const float e = __builtin_amdgcn_exp2f(p[kvb][r] - mn);
          p[kvb][r] = e; rs += e;
        }
      rs += __shfl_xor(rs, 32);
      l_run += rs;

      // ---- P^T -> bf16 B-frags in registers (cvt_pk + lane^32 exchange, T12)
      bf16x8 pb[4];
      #pragma unroll
      for (int kvb = 0; kvb < 2; ++kvb)
        #pragma unroll
        for (int s2 = 0; s2 < 2; ++s2) {
          const int rb = s2 * 8;
          const u32 k01 = cvtpk(p[kvb][rb+0], p[kvb][rb+1]);
          const u32 k23 = cvtpk(p[kvb][rb+2], p[kvb][rb+3]);
          const u32 k45 = cvtpk(p[kvb][rb+4], p[kvb][rb+5]);
          const u32 k67 = cvtpk(p[kvb][rb+6], p[kvb][rb+7]);
          const u32 sa = hi ? k01 : k45;
          const u32 sb = hi ? k23 : k67;
          const u32 ra = (u32)__shfl_xor((int)sa, 32);
          const u32 rb2 = (u32)__shfl_xor((int)sb, 32);
          u32x4 w;
          w.x = hi ? ra  : k01;
          w.y = hi ? rb2 : k23;
          w.z = hi ? k45 : ra;
          w.w = hi ? k67 : rb2;
          pb[kvb*2 + s2] = __builtin_bit_cast(bf16x8, w);
        }

      // ---- O^T += V^T P^T : D[d, q=lane&31]
      #pragma unroll
      for (int db = 0; db < 2; ++db) {
        const int vrow = db*32 + q31;
        #pragma unroll
        for (int s = 0; s < 4; ++s) {
          const int byte = (vrow*128 + s*32 + hi*16) ^ ((vrow & 7) << 4);
          const bf16x8 av = *reinterpret_cast<const bf16x8*>(
              reinterpret_cast<const char*>(Vs[cur]) + byte);
          o[db] = __builtin_amdgcn_mfma_f32_32x32x16_bf16(av, pb[s], o[db], 0, 0, 0);
        }
      }
    }
    __syncthreads();   // buf swap + DMA drain
  }
  #undef STAGE

  // ---- epilogue: normalize (lane-local), transpose via reused LDS, store
  const float inv = 1.0f / l_run;
  char* const myOb = reinterpret_cast<char*>(reinterpret_cast<u16*>(Ks) + wid * 2048);
  #pragma unroll
  for (int db = 0; db < 2; ++db)
    #pragma unroll
    for (int tq = 0; tq < 4; ++tq) {
      const int d0 = db*32 + tq*8 + hi*4;
      uint2 wv;
      wv.x = cvtpk(o[db][tq*4+0] * inv, o[db][tq*4+1] * inv);
      wv.y = cvtpk(o[db][tq*4+2] * inv, o[db][tq*4+3] * inv);
      const int byte = (q31*128 + d0*2) ^ ((q31 & 7) << 4);
      *reinterpret_cast<uint2*>(myOb + byte) = wv;
    }
  __syncthreads();
  const int b = bh >> 4, h = bh & 15;
  const int qr = l >> 1, half = l & 1;
  const int qg = qrow0 + qr;
  #pragma unroll
  for (int i = 0; i < 4; ++i) {
    const int byte = (qr*128 + half*64 + i*16) ^ ((qr & 7) << 4);
    const u32x4 v = *reinterpret_cast<const u32x4*>(myOb + byte);
    *reinterpret_cast<u32x4*>(
        &Ob[((size_t)(b * SDIM + qg)) * DMODEL + h * HDIM + half*32 + i*8]) = v;
  }
}

// ---------------------------------------------------------------- launch
extern "C" void kernel_launch(void* const* d_in, const int* in_sizes, int n_in,
                              void* d_out, int out_size, void* d_ws, size_t ws_size,
                              hipStream_t stream) {
  const float* x     = (const float*)d_in[0];
  // d_in[1] = causal mask (deterministic triu, applied analytically — unused)
  const float* w_q   = (const float*)d_in[2];
  const float* w_k   = (const float*)d_in[3];
  const float* w_v   = (const float*)d_in[4];
  const float* w_out = (const float*)d_in[5];
  float* out = (float*)d_out;

  const size_t NX = (size_t)MTOT * DMODEL;   // 8,388,608
  const size_t NW = (size_t)DMODEL * DMODEL; // 1,048,576
  u16* xb   = (u16*)d_ws;
  u16* wqb  = xb  + NX;
  u16* wkb  = wqb + NW;
  u16* wvb  = wkb + NW;
  u16* wob  = wvb + NW;
  u16* Qhd  = wob + NW;
  u16* Khd  = Qhd + NX;
  u16* Vtd  = Khd + NX;
  u16* attb = Vtd + NX;
  // total: 5*NX + 4*NW ushorts = 92.3 MB (fits ws)

  cast_bf16_kernel<<<(int)(NX/4 + 255)/256, 256, 0, stream>>>(x, xb, (int)(NX/4));
  cast_bf16_kernel<<<(int)(NW/4 + 255)/256, 256, 0, stream>>>(w_q,   wqb, (int)(NW/4));
  cast_bf16_kernel<<<(int)(NW/4 + 255)/256, 256, 0, stream>>>(w_k,   wkb, (int)(NW/4));
  cast_bf16_kernel<<<(int)(NW/4 + 255)/256, 256, 0, stream>>>(w_v,   wvb, (int)(NW/4));
  cast_bf16_kernel<<<(int)(NW/4 + 255)/256, 256, 0, stream>>>(w_out, wob, (int)(NW/4));

  const dim3 gg(DMODEL / 128, MTOT / 128);   // (8, 64)
  // Q scaled by 1/sqrt(1024) * log2(e) so softmax runs in exp2 domain
  gemm_bf16_kernel<<<gg, 256, 0, stream>>>(xb, wqb, Qhd, 1.4426950408889634f / 32.0f, 1);
  gemm_bf16_kernel<<<gg, 256, 0, stream>>>(xb, wkb, Khd, 1.0f, 1);
  gemm_bf16_kernel<<<gg, 256, 0, stream>>>(xb, wvb, Vtd, 1.0f, 2);

  attn_mfma_kernel<<<dim3(SDIM / 128, BDIM * NHEAD), 256, 0, stream>>>(Qhd, Khd, Vtd, attb);

  gemm_bf16_kernel<<<gg, 256, 0, stream>>>(attb, wob, out, 1.0f, 0);
}

// Round 6
// 325.613 us; speedup vs baseline: 10.2400x; 1.1183x over previous
//
#include <hip/hip_runtime.h>

#define BDIM 4
#define SDIM 2048
#define DMODEL 1024
#define NHEAD 16
#define HDIM 64
#define MTOT (BDIM*SDIM)          // 8192

typedef unsigned short u16;
typedef unsigned int u32;
typedef __attribute__((ext_vector_type(8))) short bf16x8;
typedef __attribute__((ext_vector_type(4))) float f32x4;
typedef __attribute__((ext_vector_type(16))) float f32x16;
typedef __attribute__((ext_vector_type(4))) u32 u32x4;

__device__ __forceinline__ u16 f2bf(float f) {
  unsigned u = __builtin_bit_cast(unsigned, f);
  u += 0x7fffu + ((u >> 16) & 1u);   // RNE to bf16
  return (u16)(u >> 16);
}

// packed f32x2 -> bf16x2 (src0 -> low half). gfx950 VOP3.
__device__ __forceinline__ u32 cvtpk(float a, float b) {
  u32 r;
  asm("v_cvt_pk_bf16_f32 %0, %1, %2" : "=v"(r) : "v"(a), "v"(b));
  return r;
}

// async global->LDS, 16B per lane. LDS dest is wave-uniform base + lane*16.
__device__ __forceinline__ void gload_lds16(const u16* g, u16* l) {
  __builtin_amdgcn_global_load_lds(
      (const __attribute__((address_space(1))) unsigned int*)g,
      (__attribute__((address_space(3))) unsigned int*)l, 16, 0, 0);
}

// ---------------------------------------------------------------- casts
__global__ __launch_bounds__(256) void cast_bf16_kernel(
    const float* __restrict__ src, u16* __restrict__ dst, int n4)
{
  const int i = blockIdx.x * 256 + threadIdx.x;
  if (i < n4) {
    const float4 v = reinterpret_cast<const float4*>(src)[i];
    unsigned long long w =
        (unsigned long long)f2bf(v.x)
      | ((unsigned long long)f2bf(v.y) << 16)
      | ((unsigned long long)f2bf(v.z) << 32)
      | ((unsigned long long)f2bf(v.w) << 48);
    reinterpret_cast<unsigned long long*>(dst)[i] = w;
  }
}

// 4 weight matrices (same size) in one launch; blockIdx.y selects.
__global__ __launch_bounds__(256) void cast_w4_kernel(
    const float* __restrict__ w0, const float* __restrict__ w1,
    const float* __restrict__ w2, const float* __restrict__ w3,
    u16* __restrict__ d0, u16* __restrict__ d1,
    u16* __restrict__ d2, u16* __restrict__ d3, int n4)
{
  const int y = blockIdx.y;
  const float* src = (y == 0) ? w0 : (y == 1) ? w1 : (y == 2) ? w2 : w3;
  u16* dst = (y == 0) ? d0 : (y == 1) ? d1 : (y == 2) ? d2 : d3;
  const int i = blockIdx.x * 256 + threadIdx.x;
  if (i < n4) {
    const float4 v = reinterpret_cast<const float4*>(src)[i];
    unsigned long long w =
        (unsigned long long)f2bf(v.x)
      | ((unsigned long long)f2bf(v.y) << 16)
      | ((unsigned long long)f2bf(v.z) << 32)
      | ((unsigned long long)f2bf(v.w) << 48);
    reinterpret_cast<unsigned long long*>(dst)[i] = w;
  }
}

// ---------------------------------------------------------------- GEMM core
// Computes a 128x128 tile of A * W^T at (m0,n0); epilogue per mode.
// mode 0: fp32 [M][1024]; mode 1: bf16 [B][H][S][64]; mode 2: bf16 [B][H][64][S]
template <int MODE>
__device__ __forceinline__ void gemm_tile(
    const u16* __restrict__ A, const u16* __restrict__ W,
    void* __restrict__ C, float scale, int m0, int n0,
    u16* As /*[2][128*32]*/, u16* Bs /*[2][128*32]*/)
{
  const int tid = threadIdx.x;
  const int l  = tid & 63, wid = tid >> 6;
  const int wr = wid >> 1, wc = wid & 1;        // 2x2 waves -> 64x64 each
  const int lc = l & 15, lr = l >> 4;
  const int ar = l >> 2;          // staging: row within 16-row group
  const int ac = (l & 3) * 8;     // staging: elem offset in 32-elem row

  const f32x4 z4 = {0.f, 0.f, 0.f, 0.f};
  f32x4 acc[4][4];
  #pragma unroll
  for (int i = 0; i < 4; ++i)
    #pragma unroll
    for (int j = 0; j < 4; ++j) acc[i][j] = z4;

  #define GSTAGE(bufi, kk)                                                        \
    { _Pragma("unroll")                                                           \
      for (int j = 0; j < 2; ++j) {                                               \
        const int row = wid * 32 + j * 16;                                        \
        gload_lds16(&A[(size_t)(m0 + row + ar) * DMODEL + (kk) + ac],             \
                    &As[(bufi) * 4096 + row * 32]);                               \
        gload_lds16(&W[(size_t)(n0 + row + ar) * DMODEL + (kk) + ac],             \
                    &Bs[(bufi) * 4096 + row * 32]);                               \
      } }

  GSTAGE(0, 0);
  __syncthreads();

  for (int ks = 0; ks < DMODEL / 32; ++ks) {
    const int cur = ks & 1;
    if (ks + 1 < DMODEL / 32) GSTAGE(cur ^ 1, (ks + 1) * 32);

    bf16x8 a[4], b[4];
    #pragma unroll
    for (int i = 0; i < 4; ++i)
      a[i] = *reinterpret_cast<const bf16x8*>(&As[cur*4096 + (wr*64 + i*16 + lc) * 32 + lr*8]);
    #pragma unroll
    for (int j = 0; j < 4; ++j)
      b[j] = *reinterpret_cast<const bf16x8*>(&Bs[cur*4096 + (wc*64 + j*16 + lc) * 32 + lr*8]);

    __builtin_amdgcn_s_setprio(1);
    #pragma unroll
    for (int i = 0; i < 4; ++i)
      #pragma unroll
      for (int j = 0; j < 4; ++j)
        acc[i][j] = __builtin_amdgcn_mfma_f32_16x16x32_bf16(a[i], b[j], acc[i][j], 0, 0, 0);
    __builtin_amdgcn_s_setprio(0);
    __syncthreads();
  }
  #undef GSTAGE

  // epilogue — C/D layout: col = lc, row = lr*4 + j
  #pragma unroll
  for (int mi = 0; mi < 4; ++mi)
    #pragma unroll
    for (int ni = 0; ni < 4; ++ni) {
      const int col = n0 + wc*64 + ni*16 + lc;
      #pragma unroll
      for (int j = 0; j < 4; ++j) {
        const int row = m0 + wr*64 + mi*16 + lr*4 + j;
        const float v = acc[mi][ni][j] * scale;
        if (MODE == 0) {
          reinterpret_cast<float*>(C)[(size_t)row * DMODEL + col] = v;
        } else if (MODE == 1) {
          const int b = row >> 11, s = row & (SDIM-1), h = col >> 6, dh = col & 63;
          reinterpret_cast<u16*>(C)[(((size_t)(b*NHEAD + h) * SDIM + s) << 6) + dh] = f2bf(v);
        } else {
          const int b = row >> 11, s = row & (SDIM-1), h = col >> 6, dh = col & 63;
          reinterpret_cast<u16*>(C)[(((size_t)(b*NHEAD + h) * HDIM + dh) << 11) + s] = f2bf(v);
        }
      }
    }
}

// XCD-aware swizzle of a 512-block (8x64) xy-slice: consecutive 64 swz ids per XCD
// -> each XCD works 8 m-panels x all n -> A panel (2MB) + W (2MB) fit its L2.
__device__ __forceinline__ void swz_tile(int& m0, int& n0) {
  const int lin = blockIdx.y * 8 + blockIdx.x;      // 0..511
  const int swz = (lin & 7) * 64 + (lin >> 3);
  m0 = (swz >> 3) * 128;
  n0 = (swz & 7) * 128;
}

// fused Q/K/V projection: z selects weight/output/scale/mode
__global__ __launch_bounds__(256) void gemm_qkv_kernel(
    const u16* __restrict__ xb,
    const u16* __restrict__ wq, const u16* __restrict__ wk, const u16* __restrict__ wv,
    u16* __restrict__ Qhd, u16* __restrict__ Khd, u16* __restrict__ Vtd)
{
  __shared__ u16 As[2 * 128 * 32];
  __shared__ u16 Bs[2 * 128 * 32];
  int m0, n0; swz_tile(m0, n0);
  const int z = blockIdx.z;
  if (z == 0)
    gemm_tile<1>(xb, wq, Qhd, 1.4426950408889634f / 32.0f, m0, n0, As, Bs);
  else if (z == 1)
    gemm_tile<1>(xb, wk, Khd, 1.0f, m0, n0, As, Bs);
  else
    gemm_tile<2>(xb, wv, Vtd, 1.0f, m0, n0, As, Bs);
}

// out-projection: bf16 in, fp32 out
__global__ __launch_bounds__(256) void gemm_out_kernel(
    const u16* __restrict__ A, const u16* __restrict__ W, float* __restrict__ C)
{
  __shared__ u16 As[2 * 128 * 32];
  __shared__ u16 Bs[2 * 128 * 32];
  int m0, n0; swz_tile(m0, n0);
  gemm_tile<0>(A, W, C, 1.0f, m0, n0, As, Bs);
}

// ---------------------------------------------------------------- MFMA flash attention
// Swapped-operand 32x32 structure (T12): S^T = mfma(K, Q^T) so each lane owns one
// q-row (q = lane&31); softmax stats are lane-local scalars. O^T = mfma(V^T, P^T).
// Qh,Kh: [B*H][S][64] bf16 (Q pre-scaled by log2e/32). Vt: [B*H][64][S] bf16.
// Ob: [B*S][1024] bf16. 4 waves x 32 q-rows = 128 q/block; KV tile 64, dbuf LDS.
__global__ __launch_bounds__(256) void attn_mfma_kernel(
    const u16* __restrict__ Qh, const u16* __restrict__ Kh,
    const u16* __restrict__ Vt, u16* __restrict__ Ob)
{
  __shared__ u16 Ks[2][64 * 64];   // [kv][d], byte ^= (kv&7)<<4
  __shared__ u16 Vs[2][64 * 64];   // [d][kv], byte ^= (d&7)<<4

  const int tid = threadIdx.x, l = tid & 63, wid = tid >> 6;
  const int q31 = l & 31, hi = l >> 5;
  const int qt = (int)gridDim.x - 1 - (int)blockIdx.x;   // heavy blocks first
  const int bh = blockIdx.y;
  const size_t base = (size_t)bh * SDIM * HDIM;
  const int qrow0 = qt * 128 + wid * 32;

  // staging lane geometry: 1 inst = 1KB = 8 rows x 128B; pre-swizzled source
  const int sr = l >> 3;
  const int sc = ((l & 7) ^ sr) * 8;

  // Q as B-frag: lane holds Q[qrow0+q31][kc*16 + hi*8 + j]
  bf16x8 aq[4];
  #pragma unroll
  for (int kc = 0; kc < 4; ++kc)
    aq[kc] = *reinterpret_cast<const bf16x8*>(
        &Qh[base + (size_t)(qrow0 + q31) * HDIM + kc*16 + hi*8]);

  f32x16 o[2], p[2];
  #pragma unroll
  for (int r = 0; r < 16; ++r) { o[0][r] = 0.f; o[1][r] = 0.f; }
  float m_run = -1e30f, l_run = 0.f;

  #define STAGE(bufi, kv0s)                                                     \
    { _Pragma("unroll")                                                         \
      for (int j = 0; j < 2; ++j) {                                             \
        const int rg = wid * 16 + j * 8;                                        \
        gload_lds16(&Kh[base + (size_t)((kv0s) + rg + sr) * HDIM + sc],         \
                    &Ks[bufi][rg * 64]);                                        \
        gload_lds16(&Vt[base + (size_t)(rg + sr) * SDIM + (kv0s) + sc],         \
                    &Vs[bufi][rg * 64]);                                        \
      } }

  const int nt = 2 * qt + 2;
  STAGE(0, 0);
  __syncthreads();

  for (int t = 0; t < nt; ++t) {
    const int kv0 = t * 64;
    const int cur = t & 1;
    if (t + 1 < nt) STAGE(cur ^ 1, kv0 + 64);   // issue-early; drains at barrier

    if (kv0 <= qrow0 + 31) {   // wave-uniform: skip fully-masked tiles
      // ---- S^T = K Q^T : D[kv, q=lane&31]
      __builtin_amdgcn_s_setprio(1);
      #pragma unroll
      for (int kvb = 0; kvb < 2; ++kvb) {
        #pragma unroll
        for (int r = 0; r < 16; ++r) p[kvb][r] = 0.f;
        const int krow = kvb*32 + q31;
        #pragma unroll
        for (int kc = 0; kc < 4; ++kc) {
          const int byte = (krow*128 + kc*32 + hi*16) ^ ((krow & 7) << 4);
          const bf16x8 ak = *reinterpret_cast<const bf16x8*>(
              reinterpret_cast<const char*>(Ks[cur]) + byte);
          p[kvb] = __builtin_amdgcn_mfma_f32_32x32x16_bf16(ak, aq[kc], p[kvb], 0, 0, 0);
        }
      }
      __builtin_amdgcn_s_setprio(0);

      // ---- causal mask (reg r holds kv = kv0 + kvb*32 + (r&3)+8*(r>>2)+4*hi)
      if (kv0 + 63 > qrow0) {
        const int q = qrow0 + q31;
        #pragma unroll
        for (int kvb = 0; kvb < 2; ++kvb)
          #pragma unroll
          for (int r = 0; r < 16; ++r) {
            const int kv = kv0 + kvb*32 + (r & 3) + 8*(r >> 2) + 4*hi;
            if (kv > q) p[kvb][r] = -1e9f;
          }
      }

      // ---- online softmax (log2 domain), lane-local + one lane^32 exchange
      float pm = -1e30f;
      #pragma unroll
      for (int r = 0; r < 16; ++r) {
        pm = fmaxf(pm, p[0][r]); pm = fmaxf(pm, p[1][r]);
      }
      pm = fmaxf(pm, __shfl_xor(pm, 32));
      float mn = m_run;
      if (!__all(pm - m_run <= 8.0f)) {      // defer-max (T13)
        mn = fmaxf(m_run, pm);
        const float al = __builtin_amdgcn_exp2f(m_run - mn);
        #pragma unroll
        for (int r = 0; r < 16; ++r) { o[0][r] *= al; o[1][r] *= al; }
        l_run *= al;
        m_run = mn;
      }
      float rs = 0.f;
      #pragma unroll
      for (int kvb = 0; kvb < 2; ++kvb)
        #pragma unroll
        for (int r = 0; r < 16; ++r) {
          const float e = __builtin_amdgcn_exp2f(p[kvb][r] - mn);
          p[kvb][r] = e; rs += e;
        }
      rs += __shfl_xor(rs, 32);
      l_run += rs;

      // ---- P^T -> bf16 B-frags in registers (cvt_pk + lane^32 exchange, T12)
      bf16x8 pb[4];
      #pragma unroll
      for (int kvb = 0; kvb < 2; ++kvb)
        #pragma unroll
        for (int s2 = 0; s2 < 2; ++s2) {
          const int rb = s2 * 8;
          const u32 k01 = cvtpk(p[kvb][rb+0], p[kvb][rb+1]);
          const u32 k23 = cvtpk(p[kvb][rb+2], p[kvb][rb+3]);
          const u32 k45 = cvtpk(p[kvb][rb+4], p[kvb][rb+5]);
          const u32 k67 = cvtpk(p[kvb][rb+6], p[kvb][rb+7]);
          const u32 sa = hi ? k01 : k45;
          const u32 sb = hi ? k23 : k67;
          const u32 ra = (u32)__shfl_xor((int)sa, 32);
          const u32 rb2 = (u32)__shfl_xor((int)sb, 32);
          u32x4 w;
          w.x = hi ? ra  : k01;
          w.y = hi ? rb2 : k23;
          w.z = hi ? k45 : ra;
          w.w = hi ? k67 : rb2;
          pb[kvb*2 + s2] = __builtin_bit_cast(bf16x8, w);
        }

      // ---- O^T += V^T P^T : D[d, q=lane&31]
      __builtin_amdgcn_s_setprio(1);
      #pragma unroll
      for (int db = 0; db < 2; ++db) {
        const int vrow = db*32 + q31;
        #pragma unroll
        for (int s = 0; s < 4; ++s) {
          const int byte = (vrow*128 + s*32 + hi*16) ^ ((vrow & 7) << 4);
          const bf16x8 av = *reinterpret_cast<const bf16x8*>(
              reinterpret_cast<const char*>(Vs[cur]) + byte);
          o[db] = __builtin_amdgcn_mfma_f32_32x32x16_bf16(av, pb[s], o[db], 0, 0, 0);
        }
      }
      __builtin_amdgcn_s_setprio(0);
    }
    __syncthreads();   // buf swap + DMA drain
  }
  #undef STAGE

  // ---- epilogue: normalize (lane-local), transpose via reused LDS, store
  const float inv = 1.0f / l_run;
  char* const myOb = reinterpret_cast<char*>(reinterpret_cast<u16*>(Ks) + wid * 2048);
  #pragma unroll
  for (int db = 0; db < 2; ++db)
    #pragma unroll
    for (int tq = 0; tq < 4; ++tq) {
      const int d0 = db*32 + tq*8 + hi*4;
      uint2 wv;
      wv.x = cvtpk(o[db][tq*4+0] * inv, o[db][tq*4+1] * inv);
      wv.y = cvtpk(o[db][tq*4+2] * inv, o[db][tq*4+3] * inv);
      const int byte = (q31*128 + d0*2) ^ ((q31 & 7) << 4);
      *reinterpret_cast<uint2*>(myOb + byte) = wv;
    }
  __syncthreads();
  const int b = bh >> 4, h = bh & 15;
  const int qr = l >> 1, half = l & 1;
  const int qg = qrow0 + qr;
  #pragma unroll
  for (int i = 0; i < 4; ++i) {
    const int byte = (qr*128 + half*64 + i*16) ^ ((qr & 7) << 4);
    const u32x4 v = *reinterpret_cast<const u32x4*>(myOb + byte);
    *reinterpret_cast<u32x4*>(
        &Ob[((size_t)(b * SDIM + qg)) * DMODEL + h * HDIM + half*32 + i*8]) = v;
  }
}

// ---------------------------------------------------------------- launch
extern "C" void kernel_launch(void* const* d_in, const int* in_sizes, int n_in,
                              void* d_out, int out_size, void* d_ws, size_t ws_size,
                              hipStream_t stream) {
  const float* x     = (const float*)d_in[0];
  // d_in[1] = causal mask (deterministic triu, applied analytically — unused)
  const float* w_q   = (const float*)d_in[2];
  const float* w_k   = (const float*)d_in[3];
  const float* w_v   = (const float*)d_in[4];
  const float* w_out = (const float*)d_in[5];
  float* out = (float*)d_out;

  const size_t NX = (size_t)MTOT * DMODEL;   // 8,388,608
  const size_t NW = (size_t)DMODEL * DMODEL; // 1,048,576
  u16* xb   = (u16*)d_ws;
  u16* wqb  = xb  + NX;
  u16* wkb  = wqb + NW;
  u16* wvb  = wkb + NW;
  u16* wob  = wvb + NW;
  u16* Qhd  = wob + NW;
  u16* Khd  = Qhd + NX;
  u16* Vtd  = Khd + NX;
  u16* attb = Vtd + NX;
  // total: 5*NX + 4*NW ushorts = 92.3 MB (fits ws)

  cast_bf16_kernel<<<(int)(NX/4 + 255)/256, 256, 0, stream>>>(x, xb, (int)(NX/4));
  cast_w4_kernel<<<dim3((int)(NW/4 + 255)/256, 4), 256, 0, stream>>>(
      w_q, w_k, w_v, w_out, wqb, wkb, wvb, wob, (int)(NW/4));

  // fused Q/K/V projection (z selects); Q scaled by log2(e)/sqrt(1024)
  gemm_qkv_kernel<<<dim3(8, 64, 3), 256, 0, stream>>>(xb, wqb, wkb, wvb, Qhd, Khd, Vtd);

  attn_mfma_kernel<<<dim3(SDIM / 128, BDIM * NHEAD), 256, 0, stream>>>(Qhd, Khd, Vtd, attb);

  gemm_out_kernel<<<dim3(8, 64), 256, 0, stream>>>(attb, wob, out);
}

// Round 13
// 306.666 us; speedup vs baseline: 10.8726x; 1.0618x over previous
//
#include <hip/hip_runtime.h>

#define BDIM 4
#define SDIM 2048
#define DMODEL 1024
#define NHEAD 16
#define HDIM 64
#define MTOT (BDIM*SDIM)          // 8192

typedef unsigned short u16;
typedef unsigned int u32;
typedef __attribute__((ext_vector_type(8))) short bf16x8;
typedef __attribute__((ext_vector_type(4))) float f32x4;
typedef __attribute__((ext_vector_type(16))) float f32x16;
typedef __attribute__((ext_vector_type(4))) u32 u32x4;
typedef __attribute__((ext_vector_type(4))) u16 u16x4;

__device__ __forceinline__ u16 f2bf(float f) {
  unsigned u = __builtin_bit_cast(unsigned, f);
  u += 0x7fffu + ((u >> 16) & 1u);   // RNE to bf16
  return (u16)(u >> 16);
}

// packed f32x2 -> bf16x2 (src0 -> low half). gfx950 VOP3.
__device__ __forceinline__ u32 cvtpk(float a, float b) {
  u32 r;
  asm("v_cvt_pk_bf16_f32 %0, %1, %2" : "=v"(r) : "v"(a), "v"(b));
  return r;
}

// async global->LDS, 16B per lane. LDS dest is wave-uniform base + lane*16.
__device__ __forceinline__ void gload_lds16(const u16* g, u16* l) {
  __builtin_amdgcn_global_load_lds(
      (const __attribute__((address_space(1))) unsigned int*)g,
      (__attribute__((address_space(3))) unsigned int*)l, 16, 0, 0);
}

// ---------------------------------------------------------------- casts
__global__ __launch_bounds__(256) void cast_bf16_kernel(
    const float* __restrict__ src, u16* __restrict__ dst, int n4)
{
  const int i = blockIdx.x * 256 + threadIdx.x;
  if (i < n4) {
    const float4 v = reinterpret_cast<const float4*>(src)[i];
    unsigned long long w =
        (unsigned long long)f2bf(v.x)
      | ((unsigned long long)f2bf(v.y) << 16)
      | ((unsigned long long)f2bf(v.z) << 32)
      | ((unsigned long long)f2bf(v.w) << 48);
    reinterpret_cast<unsigned long long*>(dst)[i] = w;
  }
}

// 4 weight matrices (same size) in one launch; blockIdx.y selects.
__global__ __launch_bounds__(256) void cast_w4_kernel(
    const float* __restrict__ w0, const float* __restrict__ w1,
    const float* __restrict__ w2, const float* __restrict__ w3,
    u16* __restrict__ d0, u16* __restrict__ d1,
    u16* __restrict__ d2, u16* __restrict__ d3, int n4)
{
  const int y = blockIdx.y;
  const float* src = (y == 0) ? w0 : (y == 1) ? w1 : (y == 2) ? w2 : w3;
  u16* dst = (y == 0) ? d0 : (y == 1) ? d1 : (y == 2) ? d2 : d3;
  const int i = blockIdx.x * 256 + threadIdx.x;
  if (i < n4) {
    const float4 v = reinterpret_cast<const float4*>(src)[i];
    unsigned long long w =
        (unsigned long long)f2bf(v.x)
      | ((unsigned long long)f2bf(v.y) << 16)
      | ((unsigned long long)f2bf(v.z) << 32)
      | ((unsigned long long)f2bf(v.w) << 48);
    reinterpret_cast<unsigned long long*>(dst)[i] = w;
  }
}

// ---------------------------------------------------------------- GEMM core
// Computes a 128x128 tile of A * W^T at (m0,n0); epilogue per mode.
// mode 0: fp32 [M][1024]; mode 1: bf16 [B][H][S][64]; mode 2: bf16 [B][H][64][S]
template <int MODE>
__device__ __forceinline__ void gemm_tile(
    const u16* __restrict__ A, const u16* __restrict__ W,
    void* __restrict__ C, float scale, int m0, int n0,
    u16* As /*[2][128*32]*/, u16* Bs /*[2][128*32]*/)
{
  const int tid = threadIdx.x;
  const int l  = tid & 63, wid = tid >> 6;
  const int wr = wid >> 1, wc = wid & 1;        // 2x2 waves -> 64x64 each
  const int lc = l & 15, lr = l >> 4;
  const int ar = l >> 2;          // staging: row within 16-row group
  const int ac = (l & 3) * 8;     // staging: elem offset in 32-elem row

  const f32x4 z4 = {0.f, 0.f, 0.f, 0.f};
  f32x4 acc[4][4];
  #pragma unroll
  for (int i = 0; i < 4; ++i)
    #pragma unroll
    for (int j = 0; j < 4; ++j) acc[i][j] = z4;

  #define GSTAGE(bufi, kk)                                                        \
    { _Pragma("unroll")                                                           \
      for (int j = 0; j < 2; ++j) {                                               \
        const int row = wid * 32 + j * 16;                                        \
        gload_lds16(&A[(size_t)(m0 + row + ar) * DMODEL + (kk) + ac],             \
                    &As[(bufi) * 4096 + row * 32]);                               \
        gload_lds16(&W[(size_t)(n0 + row + ar) * DMODEL + (kk) + ac],             \
                    &Bs[(bufi) * 4096 + row * 32]);                               \
      } }

  GSTAGE(0, 0);
  __syncthreads();

  for (int ks = 0; ks < DMODEL / 32; ++ks) {
    const int cur = ks & 1;
    if (ks + 1 < DMODEL / 32) GSTAGE(cur ^ 1, (ks + 1) * 32);

    bf16x8 a[4], b[4];
    #pragma unroll
    for (int i = 0; i < 4; ++i)
      a[i] = *reinterpret_cast<const bf16x8*>(&As[cur*4096 + (wr*64 + i*16 + lc) * 32 + lr*8]);
    #pragma unroll
    for (int j = 0; j < 4; ++j)
      b[j] = *reinterpret_cast<const bf16x8*>(&Bs[cur*4096 + (wc*64 + j*16 + lc) * 32 + lr*8]);

    __builtin_amdgcn_s_setprio(1);
    #pragma unroll
    for (int i = 0; i < 4; ++i)
      #pragma unroll
      for (int j = 0; j < 4; ++j)
        acc[i][j] = __builtin_amdgcn_mfma_f32_16x16x32_bf16(a[i], b[j], acc[i][j], 0, 0, 0);
    __builtin_amdgcn_s_setprio(0);
    __syncthreads();
  }
  #undef GSTAGE

  // epilogue — C/D layout: col = lc, row = lr*4 + j (verified m89/m91)
  #pragma unroll
  for (int mi = 0; mi < 4; ++mi)
    #pragma unroll
    for (int ni = 0; ni < 4; ++ni) {
      const int col = n0 + wc*64 + ni*16 + lc;
      if (MODE == 2) {
        // 4 consecutive-s u16 stores packed into one 8B store (same addresses
        // as the round-6 scalar path; s = row0&2047 is 4-aligned -> 8B aligned)
        const int row0 = m0 + wr*64 + mi*16 + lr*4;
        const int b = row0 >> 11, s = row0 & (SDIM-1), h = col >> 6, dh = col & 63;
        u16x4 pk;
        pk[0] = f2bf(acc[mi][ni][0] * scale);
        pk[1] = f2bf(acc[mi][ni][1] * scale);
        pk[2] = f2bf(acc[mi][ni][2] * scale);
        pk[3] = f2bf(acc[mi][ni][3] * scale);
        *reinterpret_cast<u16x4*>(
            &reinterpret_cast<u16*>(C)[(((size_t)(b*NHEAD + h) * HDIM + dh) << 11) + s]) = pk;
      } else {
        #pragma unroll
        for (int j = 0; j < 4; ++j) {
          const int row = m0 + wr*64 + mi*16 + lr*4 + j;
          const float v = acc[mi][ni][j] * scale;
          if (MODE == 0) {
            reinterpret_cast<float*>(C)[(size_t)row * DMODEL + col] = v;
          } else {
            const int b = row >> 11, s = row & (SDIM-1), h = col >> 6, dh = col & 63;
            reinterpret_cast<u16*>(C)[(((size_t)(b*NHEAD + h) * SDIM + s) << 6) + dh] = f2bf(v);
          }
        }
      }
    }
}

// XCD-aware swizzle of a 512-block (8x64) xy-slice: consecutive 64 swz ids per XCD
// -> each XCD works 8 m-panels x all n -> A panel (2MB) + W (2MB) fit its L2.
__device__ __forceinline__ void swz_tile(int& m0, int& n0) {
  const int lin = blockIdx.y * 8 + blockIdx.x;      // 0..511
  const int swz = (lin & 7) * 64 + (lin >> 3);
  m0 = (swz >> 3) * 128;
  n0 = (swz & 7) * 128;
}

// fused Q/K/V projection: z selects weight/output/scale/mode
__global__ __launch_bounds__(256) void gemm_qkv_kernel(
    const u16* __restrict__ xb,
    const u16* __restrict__ wq, const u16* __restrict__ wk, const u16* __restrict__ wv,
    u16* __restrict__ Qhd, u16* __restrict__ Khd, u16* __restrict__ Vtd)
{
  __shared__ u16 As[2 * 128 * 32];
  __shared__ u16 Bs[2 * 128 * 32];
  int m0, n0; swz_tile(m0, n0);
  const int z = blockIdx.z;
  if (z == 0)
    gemm_tile<1>(xb, wq, Qhd, 1.4426950408889634f / 32.0f, m0, n0, As, Bs);
  else if (z == 1)
    gemm_tile<1>(xb, wk, Khd, 1.0f, m0, n0, As, Bs);
  else
    gemm_tile<2>(xb, wv, Vtd, 1.0f, m0, n0, As, Bs);
}

// out-projection: bf16 in, fp32 out
__global__ __launch_bounds__(256) void gemm_out_kernel(
    const u16* __restrict__ A, const u16* __restrict__ W, float* __restrict__ C)
{
  __shared__ u16 As[2 * 128 * 32];
  __shared__ u16 Bs[2 * 128 * 32];
  int m0, n0; swz_tile(m0, n0);
  gemm_tile<0>(A, W, C, 1.0f, m0, n0, As, Bs);
}

// ---------------------------------------------------------------- MFMA flash attention
// (exact round-5 kernel: launch_bounds(256,3), no setprio — measured 112.9 us)
// Swapped-operand 32x32 structure (T12): S^T = mfma(K, Q^T) so each lane owns one
// q-row (q = lane&31); softmax stats are lane-local scalars. O^T = mfma(V^T, P^T).
// Qh,Kh: [B*H][S][64] bf16 (Q pre-scaled by log2e/32). Vt: [B*H][64][S] bf16.
// Ob: [B*S][1024] bf16. 4 waves x 32 q-rows = 128 q/block; KV tile 64, dbuf LDS.
__global__ __launch_bounds__(256, 3) void attn_mfma_kernel(
    const u16* __restrict__ Qh, const u16* __restrict__ Kh,
    const u16* __restrict__ Vt, u16* __restrict__ Ob)
{
  __shared__ u16 Ks[2][64 * 64];   // [kv][d], byte ^= (kv&7)<<4
  __shared__ u16 Vs[2][64 * 64];   // [d][kv], byte ^= (d&7)<<4

  const int tid = threadIdx.x, l = tid & 63, wid = tid >> 6;
  const int q31 = l & 31, hi = l >> 5;
  const int qt = (int)gridDim.x - 1 - (int)blockIdx.x;   // heavy blocks first
  const int bh = blockIdx.y;
  const size_t base = (size_t)bh * SDIM * HDIM;
  const int qrow0 = qt * 128 + wid * 32;

  // staging lane geometry: 1 inst = 1KB = 8 rows x 128B; pre-swizzled source
  const int sr = l >> 3;
  const int sc = ((l & 7) ^ sr) * 8;

  // Q as B-frag: lane holds Q[qrow0+q31][kc*16 + hi*8 + j]
  bf16x8 aq[4];
  #pragma unroll
  for (int kc = 0; kc < 4; ++kc)
    aq[kc] = *reinterpret_cast<const bf16x8*>(
        &Qh[base + (size_t)(qrow0 + q31) * HDIM + kc*16 + hi*8]);

  f32x16 o[2], p[2];
  #pragma unroll
  for (int r = 0; r < 16; ++r) { o[0][r] = 0.f; o[1][r] = 0.f; }
  float m_run = -1e30f, l_run = 0.f;

  #define STAGE(bufi, kv0s)                                                     \
    { _Pragma("unroll")                                                         \
      for (int j = 0; j < 2; ++j) {                                             \
        const int rg = wid * 16 + j * 8;                                        \
        gload_lds16(&Kh[base + (size_t)((kv0s) + rg + sr) * HDIM + sc],         \
                    &Ks[bufi][rg * 64]);                                        \
        gload_lds16(&Vt[base + (size_t)(rg + sr) * SDIM + (kv0s) + sc],         \
                    &Vs[bufi][rg * 64]);                                        \
      } }

  const int nt = 2 * qt + 2;
  STAGE(0, 0);
  __syncthreads();

  for (int t = 0; t < nt; ++t) {
    const int kv0 = t * 64;
    const int cur = t & 1;
    if (t + 1 < nt) STAGE(cur ^ 1, kv0 + 64);   // issue-early; drains at barrier

    if (kv0 <= qrow0 + 31) {   // wave-uniform: skip fully-masked tiles
      // ---- S^T = K Q^T : D[kv, q=lane&31]
      #pragma unroll
      for (int kvb = 0; kvb < 2; ++kvb) {
        #pragma unroll
        for (int r = 0; r < 16; ++r) p[kvb][r] = 0.f;
        const int krow = kvb*32 + q31;
        #pragma unroll
        for (int kc = 0; kc < 4; ++kc) {
          const int byte = (krow*128 + kc*32 + hi*16) ^ ((krow & 7) << 4);
          const bf16x8 ak = *reinterpret_cast<const bf16x8*>(
              reinterpret_cast<const char*>(Ks[cur]) + byte);
          p[kvb] = __builtin_amdgcn_mfma_f32_32x32x16_bf16(ak, aq[kc], p[kvb], 0, 0, 0);
        }
      }

      // ---- causal mask (reg r holds kv = kv0 + kvb*32 + (r&3)+8*(r>>2)+4*hi)
      if (kv0 + 63 > qrow0) {
        const int q = qrow0 + q31;
        #pragma unroll
        for (int kvb = 0; kvb < 2; ++kvb)
          #pragma unroll
          for (int r = 0; r < 16; ++r) {
            const int kv = kv0 + kvb*32 + (r & 3) + 8*(r >> 2) + 4*hi;
            if (kv > q) p[kvb][r] = -1e9f;
          }
      }

      // ---- online softmax (log2 domain), lane-local + one lane^32 exchange
      float pm = -1e30f;
      #pragma unroll
      for (int r = 0; r < 16; ++r) {
        pm = fmaxf(pm, p[0][r]); pm = fmaxf(pm, p[1][r]);
      }
      pm = fmaxf(pm, __shfl_xor(pm, 32));
      float mn = m_run;
      if (!__all(pm - m_run <= 8.0f)) {      // defer-max (T13)
        mn = fmaxf(m_run, pm);
        const float al = __builtin_amdgcn_exp2f(m_run - mn);
        #pragma unroll
        for (int r = 0; r < 16; ++r) { o[0][r] *= al; o[1][r] *= al; }
        l_run *= al;
        m_run = mn;
      }
      float rs = 0.f;
      #pragma unroll
      for (int kvb = 0; kvb < 2; ++kvb)
        #pragma unroll
        for (int r = 0; r < 16; ++r) {
          const float e = __builtin_amdgcn_exp2f(p[kvb][r] - mn);
          p[kvb][r] = e; rs += e;
        }
      rs += __shfl_xor(rs, 32);
      l_run += rs;

      // ---- P^T -> bf16 B-frags in registers (cvt_pk + lane^32 exchange, T12)
      bf16x8 pb[4];
      #pragma unroll
      for (int kvb = 0; kvb < 2; ++kvb)
        #pragma unroll
        for (int s2 = 0; s2 < 2; ++s2) {
          const int rb = s2 * 8;
          const u32 k01 = cvtpk(p[kvb][rb+0], p[kvb][rb+1]);
          const u32 k23 = cvtpk(p[kvb][rb+2], p[kvb][rb+3]);
          const u32 k45 = cvtpk(p[kvb][rb+4], p[kvb][rb+5]);
          const u32 k67 = cvtpk(p[kvb][rb+6], p[kvb][rb+7]);
          const u32 sa = hi ? k01 : k45;
          const u32 sb = hi ? k23 : k67;
          const u32 ra = (u32)__shfl_xor((int)sa, 32);
          const u32 rb2 = (u32)__shfl_xor((int)sb, 32);
          u32x4 w;
          w.x = hi ? ra  : k01;
          w.y = hi ? rb2 : k23;
          w.z = hi ? k45 : ra;
          w.w = hi ? k67 : rb2;
          pb[kvb*2 + s2] = __builtin_bit_cast(bf16x8, w);
        }

      // ---- O^T += V^T P^T : D[d, q=lane&31]
      #pragma unroll
      for (int db = 0; db < 2; ++db) {
        const int vrow = db*32 + q31;
        #pragma unroll
        for (int s = 0; s < 4; ++s) {
          const int byte = (vrow*128 + s*32 + hi*16) ^ ((vrow & 7) << 4);
          const bf16x8 av = *reinterpret_cast<const bf16x8*>(
              reinterpret_cast<const char*>(Vs[cur]) + byte);
          o[db] = __builtin_amdgcn_mfma_f32_32x32x16_bf16(av, pb[s], o[db], 0, 0, 0);
        }
      }
    }
    __syncthreads();   // buf swap + DMA drain
  }
  #undef STAGE

  // ---- epilogue: normalize (lane-local), transpose via reused LDS, store
  const float inv = 1.0f / l_run;
  char* const myOb = reinterpret_cast<char*>(reinterpret_cast<u16*>(Ks) + wid * 2048);
  #pragma unroll
  for (int db = 0; db < 2; ++db)
    #pragma unroll
    for (int tq = 0; tq < 4; ++tq) {
      const int d0 = db*32 + tq*8 + hi*4;
      uint2 wv;
      wv.x = cvtpk(o[db][tq*4+0] * inv, o[db][tq*4+1] * inv);
      wv.y = cvtpk(o[db][tq*4+2] * inv, o[db][tq*4+3] * inv);
      const int byte = (q31*128 + d0*2) ^ ((q31 & 7) << 4);
      *reinterpret_cast<uint2*>(myOb + byte) = wv;
    }
  __syncthreads();
  const int b = bh >> 4, h = bh & 15;
  const int qr = l >> 1, half = l & 1;
  const int qg = qrow0 + qr;
  #pragma unroll
  for (int i = 0; i < 4; ++i) {
    const int byte = (qr*128 + half*64 + i*16) ^ ((qr & 7) << 4);
    const u32x4 v = *reinterpret_cast<const u32x4*>(myOb + byte);
    *reinterpret_cast<u32x4*>(
        &Ob[((size_t)(b * SDIM + qg)) * DMODEL + h * HDIM + half*32 + i*8]) = v;
  }
}

// ---------------------------------------------------------------- launch
extern "C" void kernel_launch(void* const* d_in, const int* in_sizes, int n_in,
                              void* d_out, int out_size, void* d_ws, size_t ws_size,
                              hipStream_t stream) {
  const float* x     = (const float*)d_in[0];
  // d_in[1] = causal mask (deterministic triu, applied analytically — unused)
  const float* w_q   = (const float*)d_in[2];
  const float* w_k   = (const float*)d_in[3];
  const float* w_v   = (const float*)d_in[4];
  const float* w_out = (const float*)d_in[5];
  float* out = (float*)d_out;

  const size_t NX = (size_t)MTOT * DMODEL;   // 8,388,608
  const size_t NW = (size_t)DMODEL * DMODEL; // 1,048,576
  u16* xb   = (u16*)d_ws;
  u16* wqb  = xb  + NX;
  u16* wkb  = wqb + NW;
  u16* wvb  = wkb + NW;
  u16* wob  = wvb + NW;
  u16* Qhd  = wob + NW;
  u16* Khd  = Qhd + NX;
  u16* Vtd  = Khd + NX;
  u16* attb = Vtd + NX;
  // total: 5*NX + 4*NW ushorts = 92.3 MB (fits ws)

  cast_bf16_kernel<<<(int)(NX/4 + 255)/256, 256, 0, stream>>>(x, xb, (int)(NX/4));
  cast_w4_kernel<<<dim3((int)(NW/4 + 255)/256, 4), 256, 0, stream>>>(
      w_q, w_k, w_v, w_out, wqb, wkb, wvb, wob, (int)(NW/4));

  // fused Q/K/V projection (z selects); Q scaled by log2(e)/sqrt(1024)
  gemm_qkv_kernel<<<dim3(8, 64, 3), 256, 0, stream>>>(xb, wqb, wkb, wvb, Qhd, Khd, Vtd);

  attn_mfma_kernel<<<dim3(SDIM / 128, BDIM * NHEAD), 256, 0, stream>>>(Qhd, Khd, Vtd, attb);

  gemm_out_kernel<<<dim3(8, 64), 256, 0, stream>>>(attb, wob, out);
}